// Round 13
// baseline (179.053 us; speedup 1.0000x reference)
//
#include <hip/hip_runtime.h>
#include <cstdint>
#include <cstddef>

// Problem constants (B,L,D,H fixed by the reference)
#define BB  2
#define LL  2048
#define DD  768
#define HH  12
#define DKK 64

// Measured contract (R2-R4): inputs fp32, output fp32, bf16 intermediates OK.
// R10 lesson: 128-key attn tile -> live-reg doubling -> scratch spill. 64-key tiles.
// R12 lesson: attn chain no longer binds (~25 us); fixed harness overhead ~85 us.
// R13: BK=64 GEMMs via two 32-col half-tiles (R9 body x2 per barrier, same regs);
//      bf16 split-K partials (halve combine traffic).

typedef float f32x4 __attribute__((ext_vector_type(4)));
typedef short bf16x8 __attribute__((ext_vector_type(8)));

__device__ __forceinline__ float blo(uint32_t w) { return __uint_as_float(w << 16); }
__device__ __forceinline__ float bhi(uint32_t w) { return __uint_as_float(w & 0xffff0000u); }
__device__ __forceinline__ uint16_t f2bf(float f) {
  uint32_t x = __float_as_uint(f);
  x += 0x7fffu + ((x >> 16) & 1u);   // round-to-nearest-even
  return (uint16_t)(x >> 16);
}

// async global->LDS, 16B per lane; LDS dest = wave-uniform base + lane*16
__device__ __forceinline__ void gl_lds16(const void* g, void* l) {
  __builtin_amdgcn_global_load_lds(
      (const __attribute__((address_space(1))) void*)g,
      (__attribute__((address_space(3))) void*)l, 16, 0, 0);
}

// ============================================================================
// Fused converts (one launch): x->xb (bf16), Wqkv->WqT (bf16,T), Wo->WoT.
// ============================================================================
__global__ __launch_bounds__(256) void cvt_all(
    const float* __restrict__ X, const float* __restrict__ Wq,
    const float* __restrict__ Wo, uint16_t* __restrict__ Xb,
    uint16_t* __restrict__ WqT, uint16_t* __restrict__ WoT)
{
  const int bid = blockIdx.x;
  const int t = threadIdx.x;
  if (bid < 1536) {
    const size_t i = ((size_t)bid * 256 + t) * 8;
    float4 f0 = *(const float4*)(X + i), f1 = *(const float4*)(X + i + 4);
    uint16_t o[8] = {f2bf(f0.x), f2bf(f0.y), f2bf(f0.z), f2bf(f0.w),
                     f2bf(f1.x), f2bf(f1.y), f2bf(f1.z), f2bf(f1.w)};
    *(uint4*)(Xb + i) = *(const uint4*)o;
    return;
  }
  __shared__ float tile[32][33];
  const float* W; uint16_t* WT; int R, C, bx, by;
  if (bid < 3264) { W = Wq; WT = WqT; R = 768; C = 2304; const int b2 = bid - 1536; bx = b2 % 72; by = b2 / 72; }
  else            { W = Wo; WT = WoT; R = 768; C = 768;  const int b2 = bid - 3264; bx = b2 % 24; by = b2 / 24; }
  const int tx = t & 31, ty = t >> 5;
  const int c0 = bx * 32, r0 = by * 32;
#pragma unroll
  for (int i = 0; i < 4; ++i)
    tile[ty + i * 8][tx] = W[(size_t)(r0 + ty + i * 8) * C + c0 + tx];
  __syncthreads();
#pragma unroll
  for (int i = 0; i < 4; ++i)
    WT[(size_t)(c0 + ty + i * 8) * R + r0 + tx] = f2bf(tile[tx][ty + i * 8]);
}

// ============================================================================
// MFMA GEMM, BK=64 via two 32-col half-tiles. Each half-tile is the verified
// R9 layout (128 rows x 32 cols, stride 32 elems, gl_lds16 staging) — two R9
// sub-iterations per barrier pair: half the barriers, same register live-set.
// EPI 0: scatter bf16 -> Q,K (B,H,L,DK) and V transposed (B,H,DK,L)
// EPI 1: fp32 row-major store
// ============================================================================
template <int EPI, int NN, int KDIM>
__global__ __launch_bounds__(256) void gemm_mfma(
    const uint16_t* __restrict__ A, const uint16_t* __restrict__ BT,
    const float* __restrict__ bias, float* __restrict__ OutF,
    uint16_t* __restrict__ Qo, uint16_t* __restrict__ Ko, uint16_t* __restrict__ Vo)
{
  __shared__ __align__(16) uint16_t As0[128 * 32];
  __shared__ __align__(16) uint16_t As1[128 * 32];
  __shared__ __align__(16) uint16_t Bs0[128 * 32];
  __shared__ __align__(16) uint16_t Bs1[128 * 32];
  const int t = threadIdx.x;
  const int w = t >> 6, lane = t & 63;
  const int ln = lane & 15, quad = lane >> 4;
  const int wm = w & 1, wn = w >> 1;
  const int m0 = blockIdx.x * 128, n0 = blockIdx.y * 128;
  const int lrow = lane >> 2, lcol = (lane & 3) * 8;   // staging lane map (R9)

  f32x4 acc[4][4];
#pragma unroll
  for (int mt = 0; mt < 4; ++mt)
#pragma unroll
    for (int nt = 0; nt < 4; ++nt) acc[mt][nt] = (f32x4){0.f, 0.f, 0.f, 0.f};

  for (int k0 = 0; k0 < KDIM; k0 += 64) {
    __syncthreads();
#pragma unroll
    for (int j = 0; j < 2; ++j) {
      const int row = w * 32 + j * 16;
      const size_t ra = (size_t)(m0 + row + lrow) * KDIM + k0 + lcol;
      const size_t rb = (size_t)(n0 + row + lrow) * KDIM + k0 + lcol;
      gl_lds16(A  + ra,      &As0[row * 32]);
      gl_lds16(A  + ra + 32, &As1[row * 32]);
      gl_lds16(BT + rb,      &Bs0[row * 32]);
      gl_lds16(BT + rb + 32, &Bs1[row * 32]);
    }
    __syncthreads();
#pragma unroll
    for (int s = 0; s < 2; ++s) {
      const uint16_t* Ap = s ? As1 : As0;
      const uint16_t* Bp = s ? Bs1 : Bs0;
      bf16x8 af[4], bf[4];
#pragma unroll
      for (int mt = 0; mt < 4; ++mt)
        af[mt] = *(const bf16x8*)&Ap[(wm * 64 + mt * 16 + ln) * 32 + quad * 8];
#pragma unroll
      for (int nt = 0; nt < 4; ++nt)
        bf[nt] = *(const bf16x8*)&Bp[(wn * 64 + nt * 16 + ln) * 32 + quad * 8];
#pragma unroll
      for (int mt = 0; mt < 4; ++mt)
#pragma unroll
        for (int nt = 0; nt < 4; ++nt)
          acc[mt][nt] = __builtin_amdgcn_mfma_f32_16x16x32_bf16(af[mt], bf[nt], acc[mt][nt], 0, 0, 0);
    }
  }

  if constexpr (EPI == 0) {
    const size_t S3 = (size_t)HH * LL * DKK;
    uint16_t* dstb[4]; size_t coff[4]; int isv[4]; float bv[4];
#pragma unroll
    for (int nt = 0; nt < 4; ++nt) {
      const int n = n0 + wn * 64 + nt * 16 + ln;
      bv[nt] = bias[n];
      const int which = n / 768, rem = n - which * 768;
      const int h = rem >> 6, d = rem & 63;
      isv[nt] = (which == 2);
      if (which == 2) { dstb[nt] = Vo; coff[nt] = (size_t)(h * DKK + d) * LL; }  // V^T: [h][d][l]
      else { dstb[nt] = (which == 0) ? Qo : Ko; coff[nt] = (size_t)h * LL * DKK + d; }
    }
#pragma unroll
    for (int mt = 0; mt < 4; ++mt)
#pragma unroll
      for (int r = 0; r < 4; ++r) {
        const int m = m0 + wm * 64 + mt * 16 + quad * 4 + r;
        const int b = m >> 11, l = m & 2047;
        const size_t rb = (size_t)b * S3;
#pragma unroll
        for (int nt = 0; nt < 4; ++nt) {
          const size_t idx = isv[nt] ? (rb + coff[nt] + l) : (rb + (size_t)l * DKK + coff[nt]);
          dstb[nt][idx] = f2bf(acc[mt][nt][r] + bv[nt]);
        }
      }
  } else {
    float bv[4];
#pragma unroll
    for (int nt = 0; nt < 4; ++nt) bv[nt] = bias[n0 + wn * 64 + nt * 16 + ln];
#pragma unroll
    for (int mt = 0; mt < 4; ++mt)
#pragma unroll
      for (int r = 0; r < 4; ++r) {
        const int m = m0 + wm * 64 + mt * 16 + quad * 4 + r;
        float* op = OutF + (size_t)m * NN + n0 + wn * 64;
#pragma unroll
        for (int nt = 0; nt < 4; ++nt) op[nt * 16 + ln] = acc[mt][nt][r] + bv[nt];
      }
  }
}

// ============================================================================
// Split-K MFMA causal flash attention, fixed-shift softmax (R8/R9 body,
// verified). Chunks of <=8 key-tiles (R12 mapping). Partials now bf16.
// Grid (80, B*H): bx<32: qt=24+(bx>>2), 4 chunks | bx<56: qt=16+(bx-32)/3,
// 3 chunks | bx<72: qt=8+((bx-56)>>1), 2 chunks | else qt=bx-72, direct.
// ============================================================================
__global__ __launch_bounds__(256) void attn_mfma(
    const uint16_t* __restrict__ Q, const uint16_t* __restrict__ K,
    const uint16_t* __restrict__ Vt, uint16_t* __restrict__ Y,
    uint16_t* __restrict__ partO, float* __restrict__ partL)
{
  __shared__ __align__(16) uint16_t Ks[64 * 72];      // [key][dk]
  __shared__ __align__(16) uint16_t Vs[64 * 72];      // [dk][key]
  __shared__ __align__(16) uint16_t Pq[4][16 * 72];   // per-wave [q][key]

  const int bx = blockIdx.x, bh = blockIdx.y;
  int qt, j, c;
  if (bx < 32)      { qt = 24 + (bx >> 2); j = bx & 3; c = 4; }
  else if (bx < 56) { const int b2 = bx - 32; qt = 16 + b2 / 3; j = b2 % 3; c = 3; }
  else if (bx < 72) { const int b2 = bx - 56; qt = 8 + (b2 >> 1); j = b2 & 1; c = 2; }
  else              { qt = bx - 72; j = 0; c = 1; }
  const int n = qt + 1;
  const int c0 = j * n / c;
  const int cn = (j + 1) * n / c - c0;
  const int slot = (c > 1) ? (bh * 72 + bx) : -1;

  const int q0 = qt * 64;
  const int t = threadIdx.x;
  const int w = t >> 6, lane = t & 63;
  const int ln = lane & 15, quad = lane >> 4;
  const size_t base = (size_t)bh * LL * DKK;

  bf16x8 qf0, qf1;
  {
    const uint16_t* qg = Q + base + (size_t)(q0 + w * 16 + ln) * DKK + quad * 8;
    qf0 = *(const bf16x8*)(qg);
    qf1 = *(const bf16x8*)(qg + 32);
  }

  f32x4 O[4];
#pragma unroll
  for (int nt = 0; nt < 4; ++nt) O[nt] = (f32x4){0.f, 0.f, 0.f, 0.f};
  float l_q = 0.f;

  const int srow = t >> 2, scol = (t & 3) * 16;
  const uint16_t* kgb = K  + base + (size_t)srow * DKK + scol;
  const uint16_t* vgb = Vt + base + (size_t)srow * LL  + scol;

  uint4 ka, kb, va, vb;
  {
    const size_t k0 = (size_t)c0 * 64;
    ka = *(const uint4*)(kgb + k0 * DKK + 0);  kb = *(const uint4*)(kgb + k0 * DKK + 8);
    va = *(const uint4*)(vgb + k0 + 0);        vb = *(const uint4*)(vgb + k0 + 8);
  }

  for (int i = 0; i < cn; ++i) {
    const int kt = c0 + i;
    __syncthreads();
    *(uint4*)&Ks[srow * 72 + scol + 0] = ka;
    *(uint4*)&Ks[srow * 72 + scol + 8] = kb;
    *(uint4*)&Vs[srow * 72 + scol + 0] = va;
    *(uint4*)&Vs[srow * 72 + scol + 8] = vb;
    __syncthreads();
    if (i + 1 < cn) {
      const size_t k1 = (size_t)(kt + 1) * 64;
      ka = *(const uint4*)(kgb + k1 * DKK + 0);
      kb = *(const uint4*)(kgb + k1 * DKK + 8);
      va = *(const uint4*)(vgb + k1 + 0);
      vb = *(const uint4*)(vgb + k1 + 8);
    }

    f32x4 S[4];
#pragma unroll
    for (int mt = 0; mt < 4; ++mt) {
      S[mt] = (f32x4){0.f, 0.f, 0.f, 0.f};
      const uint16_t* kp = &Ks[(mt * 16 + ln) * 72 + quad * 8];
      S[mt] = __builtin_amdgcn_mfma_f32_16x16x32_bf16(*(const bf16x8*)kp, qf0, S[mt], 0, 0, 0);
      S[mt] = __builtin_amdgcn_mfma_f32_16x16x32_bf16(*(const bf16x8*)(kp + 32), qf1, S[mt], 0, 0, 0);
    }

    float p[16];
    if (kt == qt) {
      const int qg = q0 + w * 16 + ln;
      const int k0i = kt * 64;
#pragma unroll
      for (int mt = 0; mt < 4; ++mt)
#pragma unroll
        for (int r = 0; r < 4; ++r) {
          const int key = k0i + mt * 16 + quad * 4 + r;
          const float s = (key > qg) ? -1e30f : (S[mt][r] * 0.125f - 8.f);
          p[mt * 4 + r] = __expf(s);
        }
    } else {
#pragma unroll
      for (int mt = 0; mt < 4; ++mt)
#pragma unroll
        for (int r = 0; r < 4; ++r)
          p[mt * 4 + r] = __expf(S[mt][r] * 0.125f - 8.f);
    }
    float rs = 0.f;
#pragma unroll
    for (int i2 = 0; i2 < 16; ++i2) rs += p[i2];
    l_q += rs;

#pragma unroll
    for (int mt = 0; mt < 4; ++mt) {
      uint2 pk;
      pk.x = (uint32_t)f2bf(p[mt * 4 + 0]) | ((uint32_t)f2bf(p[mt * 4 + 1]) << 16);
      pk.y = (uint32_t)f2bf(p[mt * 4 + 2]) | ((uint32_t)f2bf(p[mt * 4 + 3]) << 16);
      *(uint2*)&Pq[w][ln * 72 + mt * 16 + quad * 4] = pk;
    }

    {
      const uint16_t* pr = &Pq[w][ln * 72 + quad * 8];
      const bf16x8 pf0 = *(const bf16x8*)pr;
      const bf16x8 pf1 = *(const bf16x8*)(pr + 32);
#pragma unroll
      for (int nt = 0; nt < 4; ++nt) {
        const uint16_t* vp = &Vs[(nt * 16 + ln) * 72 + quad * 8];
        O[nt] = __builtin_amdgcn_mfma_f32_16x16x32_bf16(pf0, *(const bf16x8*)vp, O[nt], 0, 0, 0);
        O[nt] = __builtin_amdgcn_mfma_f32_16x16x32_bf16(pf1, *(const bf16x8*)(vp + 32), O[nt], 0, 0, 0);
      }
    }
  }

  l_q += __shfl_xor(l_q, 16);
  l_q += __shfl_xor(l_q, 32);

  if (slot < 0) {
    const int b = bh / HH, h = bh - b * HH;
    f32x4 iv;
#pragma unroll
    for (int r = 0; r < 4; ++r) iv[r] = 1.f / __shfl(l_q, quad * 4 + r);
#pragma unroll
    for (int nt = 0; nt < 4; ++nt) {
      const f32x4 o = O[nt] * iv;
#pragma unroll
      for (int r = 0; r < 4; ++r) {
        const int row = q0 + w * 16 + quad * 4 + r;
        Y[((size_t)(b * LL + row)) * DD + h * DKK + nt * 16 + ln] = f2bf(o[r]);
      }
    }
  } else {
    uint16_t* po = partO + (size_t)slot * 4096;
#pragma unroll
    for (int nt = 0; nt < 4; ++nt)
#pragma unroll
      for (int r = 0; r < 4; ++r)
        po[(w * 16 + quad * 4 + r) * 64 + nt * 16 + ln] = f2bf(O[nt][r]);
    if (quad == 0) partL[slot * 64 + w * 16 + ln] = l_q;
  }
}

// ============================================================================
// Combine bf16 partials: grid (24, B*H), cx -> qt = 8+cx; m = 2/3/4 chunks at
// contiguous bx slots (see attn_mfma mapping). Y = sum(O_i) / sum(l_i).
// ============================================================================
__global__ __launch_bounds__(256) void attn_combine(
    const uint16_t* __restrict__ partO, const float* __restrict__ partL,
    uint16_t* __restrict__ Y)
{
  const int cx = blockIdx.x, bh = blockIdx.y;
  const int qt = 8 + cx, q0 = qt * 64;
  int m, bbx;
  if (cx >= 16)     { m = 4; bbx = (cx - 16) * 4; }
  else if (cx >= 8) { m = 3; bbx = 32 + (cx - 8) * 3; }
  else              { m = 2; bbx = 56 + cx * 2; }
  const int sbase = bh * 72 + bbx;
  const int t = threadIdx.x;
  const int q = t >> 2, d0 = (t & 3) * 16;

  float lsum = 0.f;
  for (int i = 0; i < m; ++i) lsum += partL[(sbase + i) * 64 + q];
  const float inv = 1.f / lsum;

  float acc[16];
#pragma unroll
  for (int k = 0; k < 16; ++k) acc[k] = 0.f;
  for (int i = 0; i < m; ++i) {
    const uint16_t* pp = partO + (size_t)(sbase + i) * 4096 + q * 64 + d0;
    const uint4 v0 = *(const uint4*)(pp + 0);
    const uint4 v1 = *(const uint4*)(pp + 8);
    const uint32_t wv[8] = {v0.x, v0.y, v0.z, v0.w, v1.x, v1.y, v1.z, v1.w};
#pragma unroll
    for (int k = 0; k < 8; ++k) {
      acc[2 * k + 0] += blo(wv[k]);
      acc[2 * k + 1] += bhi(wv[k]);
    }
  }
  uint16_t ov[16];
#pragma unroll
  for (int k = 0; k < 16; ++k) ov[k] = f2bf(acc[k] * inv);
  const int b = bh / HH, h = bh - b * HH;
  uint16_t* yp = Y + ((size_t)(b * LL + q0 + q)) * DD + h * DKK + d0;
  *(uint4*)(yp + 0) = *(const uint4*)&ov[0];
  *(uint4*)(yp + 8) = *(const uint4*)&ov[8];
}

// ============================================================================
extern "C" void kernel_launch(void* const* d_in, const int* in_sizes, int n_in,
                              void* d_out, int out_size, void* d_ws, size_t ws_size,
                              hipStream_t stream) {
  // Resolve inputs by element count (all six distinct) — order-proof.
  const float *x = nullptr, *Wqkv = nullptr, *bqkv = nullptr, *Wo = nullptr, *bo = nullptr;
  for (int i = 0; i < n_in; ++i) {
    switch (in_sizes[i]) {
      case 3145728: x    = (const float*)d_in[i]; break;  // (2,2048,768)
      case 4194304: /* causal mask applied analytically */ break;
      case 1769472: Wqkv = (const float*)d_in[i]; break;  // (768,2304)
      case 2304:    bqkv = (const float*)d_in[i]; break;
      case 589824:  Wo   = (const float*)d_in[i]; break;  // (768,768)
      case 768:     bo   = (const float*)d_in[i]; break;
    }
  }
  float* out = (float*)d_out;

  // ws (bf16 unless noted): xb | WqT | WoT | Q | K | Vt | partO(bf16) | partL(f32)
  uint16_t* xb  = (uint16_t*)d_ws;          // 3,145,728 elems
  uint16_t* WqT = xb  + 3145728;            // 1,769,472
  uint16_t* WoT = WqT + 1769472;            //   589,824
  uint16_t* Qp  = WoT + 589824;             // 3,145,728 each
  uint16_t* Kp  = Qp + 3145728;
  uint16_t* Vtp = Kp + 3145728;             // V transposed (B,H,DK,L)
  uint16_t* partO = Vtp + 3145728;          // 1728 slots x 4096 bf16 (14.2 MB)
  float* partL  = (float*)(partO + (size_t)1728 * 4096);  // 1728 x 64 f32
  uint16_t* Yp  = xb;                       // alias (xb dead after gemm_qkv)

  hipLaunchKernelGGL(cvt_all, dim3(3840), dim3(256), 0, stream, x, Wqkv, Wo, xb, WqT, WoT);
  hipLaunchKernelGGL((gemm_mfma<0, 2304, 768>), dim3(32, 18), dim3(256), 0, stream,
                     xb, WqT, bqkv, (float*)nullptr, Qp, Kp, Vtp);
  hipLaunchKernelGGL(attn_mfma, dim3(80, BB * HH), dim3(256), 0, stream,
                     Qp, Kp, Vtp, Yp, partO, partL);
  hipLaunchKernelGGL(attn_combine, dim3(24, BB * HH), dim3(256), 0, stream,
                     partO, partL, Yp);
  hipLaunchKernelGGL((gemm_mfma<1, 768, 768>), dim3(32, 6), dim3(256), 0, stream,
                     Yp, WoT, bo, out, (uint16_t*)nullptr, (uint16_t*)nullptr, (uint16_t*)nullptr);
}

// Round 14
// 172.785 us; speedup vs baseline: 1.0363x; 1.0363x over previous
//
#include <hip/hip_runtime.h>
#include <cstdint>
#include <cstddef>

// Problem constants (B,L,D,H fixed by the reference)
#define BB  2
#define LL  2048
#define DD  768
#define HH  12
#define DKK 64

// Measured contract (R2-R4): inputs fp32, output fp32, bf16 intermediates OK.
// R10 lesson: 128-key attn tile -> reg spill. Keep 64-key tiles.
// R13 lesson: BK=64 GEMM (2-barrier structure) regresses ~6 us (m132 analog:
//   barrier-amortization vs staging-burst/occupancy at net loss). Keep BK=32.
// Kept from R13: bf16 split-K partials (traffic-only win, absmax unchanged).

typedef float f32x4 __attribute__((ext_vector_type(4)));
typedef short bf16x8 __attribute__((ext_vector_type(8)));

__device__ __forceinline__ float blo(uint32_t w) { return __uint_as_float(w << 16); }
__device__ __forceinline__ float bhi(uint32_t w) { return __uint_as_float(w & 0xffff0000u); }
__device__ __forceinline__ uint16_t f2bf(float f) {
  uint32_t x = __float_as_uint(f);
  x += 0x7fffu + ((x >> 16) & 1u);   // round-to-nearest-even
  return (uint16_t)(x >> 16);
}

// async global->LDS, 16B per lane; LDS dest = wave-uniform base + lane*16
__device__ __forceinline__ void gl_lds16(const void* g, void* l) {
  __builtin_amdgcn_global_load_lds(
      (const __attribute__((address_space(1))) void*)g,
      (__attribute__((address_space(3))) void*)l, 16, 0, 0);
}

// ============================================================================
// Fused converts (one launch): x->xb (bf16), Wqkv->WqT (bf16,T), Wo->WoT.
// ============================================================================
__global__ __launch_bounds__(256) void cvt_all(
    const float* __restrict__ X, const float* __restrict__ Wq,
    const float* __restrict__ Wo, uint16_t* __restrict__ Xb,
    uint16_t* __restrict__ WqT, uint16_t* __restrict__ WoT)
{
  const int bid = blockIdx.x;
  const int t = threadIdx.x;
  if (bid < 1536) {
    const size_t i = ((size_t)bid * 256 + t) * 8;
    float4 f0 = *(const float4*)(X + i), f1 = *(const float4*)(X + i + 4);
    uint16_t o[8] = {f2bf(f0.x), f2bf(f0.y), f2bf(f0.z), f2bf(f0.w),
                     f2bf(f1.x), f2bf(f1.y), f2bf(f1.z), f2bf(f1.w)};
    *(uint4*)(Xb + i) = *(const uint4*)o;
    return;
  }
  __shared__ float tile[32][33];
  const float* W; uint16_t* WT; int R, C, bx, by;
  if (bid < 3264) { W = Wq; WT = WqT; R = 768; C = 2304; const int b2 = bid - 1536; bx = b2 % 72; by = b2 / 72; }
  else            { W = Wo; WT = WoT; R = 768; C = 768;  const int b2 = bid - 3264; bx = b2 % 24; by = b2 / 24; }
  const int tx = t & 31, ty = t >> 5;
  const int c0 = bx * 32, r0 = by * 32;
#pragma unroll
  for (int i = 0; i < 4; ++i)
    tile[ty + i * 8][tx] = W[(size_t)(r0 + ty + i * 8) * C + c0 + tx];
  __syncthreads();
#pragma unroll
  for (int i = 0; i < 4; ++i)
    WT[(size_t)(c0 + ty + i * 8) * R + r0 + tx] = f2bf(tile[tx][ty + i * 8]);
}

// ============================================================================
// MFMA GEMM with global_load_lds staging (R9, verified best). 128x128, BK=32.
// EPI 0: scatter bf16 -> Q,K (B,H,L,DK) and V transposed (B,H,DK,L)
// EPI 1: fp32 row-major store
// ============================================================================
template <int EPI, int NN, int KDIM>
__global__ __launch_bounds__(256) void gemm_mfma(
    const uint16_t* __restrict__ A, const uint16_t* __restrict__ BT,
    const float* __restrict__ bias, float* __restrict__ OutF,
    uint16_t* __restrict__ Qo, uint16_t* __restrict__ Ko, uint16_t* __restrict__ Vo)
{
  __shared__ __align__(16) uint16_t As[128 * 32];
  __shared__ __align__(16) uint16_t Bs[128 * 32];
  const int t = threadIdx.x;
  const int w = t >> 6, lane = t & 63;
  const int ln = lane & 15, quad = lane >> 4;
  const int wm = w & 1, wn = w >> 1;
  const int m0 = blockIdx.x * 128, n0 = blockIdx.y * 128;
  const int lrow = lane >> 2, lcol = (lane & 3) * 8;   // staging lane map

  f32x4 acc[4][4];
#pragma unroll
  for (int mt = 0; mt < 4; ++mt)
#pragma unroll
    for (int nt = 0; nt < 4; ++nt) acc[mt][nt] = (f32x4){0.f, 0.f, 0.f, 0.f};

  for (int k0 = 0; k0 < KDIM; k0 += 32) {
    __syncthreads();
#pragma unroll
    for (int j = 0; j < 2; ++j) {
      const int row = w * 32 + j * 16;
      gl_lds16(A  + (size_t)(m0 + row + lrow) * KDIM + k0 + lcol, &As[row * 32]);
      gl_lds16(BT + (size_t)(n0 + row + lrow) * KDIM + k0 + lcol, &Bs[row * 32]);
    }
    __syncthreads();
    bf16x8 af[4], bf[4];
#pragma unroll
    for (int mt = 0; mt < 4; ++mt)
      af[mt] = *(const bf16x8*)&As[(wm * 64 + mt * 16 + ln) * 32 + quad * 8];
#pragma unroll
    for (int nt = 0; nt < 4; ++nt)
      bf[nt] = *(const bf16x8*)&Bs[(wn * 64 + nt * 16 + ln) * 32 + quad * 8];
#pragma unroll
    for (int mt = 0; mt < 4; ++mt)
#pragma unroll
      for (int nt = 0; nt < 4; ++nt)
        acc[mt][nt] = __builtin_amdgcn_mfma_f32_16x16x32_bf16(af[mt], bf[nt], acc[mt][nt], 0, 0, 0);
  }

  if constexpr (EPI == 0) {
    const size_t S3 = (size_t)HH * LL * DKK;
    uint16_t* dstb[4]; size_t coff[4]; int isv[4]; float bv[4];
#pragma unroll
    for (int nt = 0; nt < 4; ++nt) {
      const int n = n0 + wn * 64 + nt * 16 + ln;
      bv[nt] = bias[n];
      const int which = n / 768, rem = n - which * 768;
      const int h = rem >> 6, d = rem & 63;
      isv[nt] = (which == 2);
      if (which == 2) { dstb[nt] = Vo; coff[nt] = (size_t)(h * DKK + d) * LL; }  // V^T: [h][d][l]
      else { dstb[nt] = (which == 0) ? Qo : Ko; coff[nt] = (size_t)h * LL * DKK + d; }
    }
#pragma unroll
    for (int mt = 0; mt < 4; ++mt)
#pragma unroll
      for (int r = 0; r < 4; ++r) {
        const int m = m0 + wm * 64 + mt * 16 + quad * 4 + r;
        const int b = m >> 11, l = m & 2047;
        const size_t rb = (size_t)b * S3;
#pragma unroll
        for (int nt = 0; nt < 4; ++nt) {
          const size_t idx = isv[nt] ? (rb + coff[nt] + l) : (rb + (size_t)l * DKK + coff[nt]);
          dstb[nt][idx] = f2bf(acc[mt][nt][r] + bv[nt]);
        }
      }
  } else {
    float bv[4];
#pragma unroll
    for (int nt = 0; nt < 4; ++nt) bv[nt] = bias[n0 + wn * 64 + nt * 16 + ln];
#pragma unroll
    for (int mt = 0; mt < 4; ++mt)
#pragma unroll
      for (int r = 0; r < 4; ++r) {
        const int m = m0 + wm * 64 + mt * 16 + quad * 4 + r;
        float* op = OutF + (size_t)m * NN + n0 + wn * 64;
#pragma unroll
        for (int nt = 0; nt < 4; ++nt) op[nt * 16 + ln] = acc[mt][nt][r] + bv[nt];
      }
  }
}

// ============================================================================
// Split-K MFMA causal flash attention, fixed-shift softmax (R8/R9 body,
// verified). Chunks of <=8 key-tiles (R12 mapping). bf16 partials (R13).
// Grid (80, B*H): bx<32: qt=24+(bx>>2), 4 chunks | bx<56: qt=16+(bx-32)/3,
// 3 chunks | bx<72: qt=8+((bx-56)>>1), 2 chunks | else qt=bx-72, direct.
// ============================================================================
__global__ __launch_bounds__(256) void attn_mfma(
    const uint16_t* __restrict__ Q, const uint16_t* __restrict__ K,
    const uint16_t* __restrict__ Vt, uint16_t* __restrict__ Y,
    uint16_t* __restrict__ partO, float* __restrict__ partL)
{
  __shared__ __align__(16) uint16_t Ks[64 * 72];      // [key][dk]
  __shared__ __align__(16) uint16_t Vs[64 * 72];      // [dk][key]
  __shared__ __align__(16) uint16_t Pq[4][16 * 72];   // per-wave [q][key]

  const int bx = blockIdx.x, bh = blockIdx.y;
  int qt, j, c;
  if (bx < 32)      { qt = 24 + (bx >> 2); j = bx & 3; c = 4; }
  else if (bx < 56) { const int b2 = bx - 32; qt = 16 + b2 / 3; j = b2 % 3; c = 3; }
  else if (bx < 72) { const int b2 = bx - 56; qt = 8 + (b2 >> 1); j = b2 & 1; c = 2; }
  else              { qt = bx - 72; j = 0; c = 1; }
  const int n = qt + 1;
  const int c0 = j * n / c;
  const int cn = (j + 1) * n / c - c0;
  const int slot = (c > 1) ? (bh * 72 + bx) : -1;

  const int q0 = qt * 64;
  const int t = threadIdx.x;
  const int w = t >> 6, lane = t & 63;
  const int ln = lane & 15, quad = lane >> 4;
  const size_t base = (size_t)bh * LL * DKK;

  bf16x8 qf0, qf1;
  {
    const uint16_t* qg = Q + base + (size_t)(q0 + w * 16 + ln) * DKK + quad * 8;
    qf0 = *(const bf16x8*)(qg);
    qf1 = *(const bf16x8*)(qg + 32);
  }

  f32x4 O[4];
#pragma unroll
  for (int nt = 0; nt < 4; ++nt) O[nt] = (f32x4){0.f, 0.f, 0.f, 0.f};
  float l_q = 0.f;

  const int srow = t >> 2, scol = (t & 3) * 16;
  const uint16_t* kgb = K  + base + (size_t)srow * DKK + scol;
  const uint16_t* vgb = Vt + base + (size_t)srow * LL  + scol;

  uint4 ka, kb, va, vb;
  {
    const size_t k0 = (size_t)c0 * 64;
    ka = *(const uint4*)(kgb + k0 * DKK + 0);  kb = *(const uint4*)(kgb + k0 * DKK + 8);
    va = *(const uint4*)(vgb + k0 + 0);        vb = *(const uint4*)(vgb + k0 + 8);
  }

  for (int i = 0; i < cn; ++i) {
    const int kt = c0 + i;
    __syncthreads();
    *(uint4*)&Ks[srow * 72 + scol + 0] = ka;
    *(uint4*)&Ks[srow * 72 + scol + 8] = kb;
    *(uint4*)&Vs[srow * 72 + scol + 0] = va;
    *(uint4*)&Vs[srow * 72 + scol + 8] = vb;
    __syncthreads();
    if (i + 1 < cn) {
      const size_t k1 = (size_t)(kt + 1) * 64;
      ka = *(const uint4*)(kgb + k1 * DKK + 0);
      kb = *(const uint4*)(kgb + k1 * DKK + 8);
      va = *(const uint4*)(vgb + k1 + 0);
      vb = *(const uint4*)(vgb + k1 + 8);
    }

    f32x4 S[4];
#pragma unroll
    for (int mt = 0; mt < 4; ++mt) {
      S[mt] = (f32x4){0.f, 0.f, 0.f, 0.f};
      const uint16_t* kp = &Ks[(mt * 16 + ln) * 72 + quad * 8];
      S[mt] = __builtin_amdgcn_mfma_f32_16x16x32_bf16(*(const bf16x8*)kp, qf0, S[mt], 0, 0, 0);
      S[mt] = __builtin_amdgcn_mfma_f32_16x16x32_bf16(*(const bf16x8*)(kp + 32), qf1, S[mt], 0, 0, 0);
    }

    float p[16];
    if (kt == qt) {
      const int qg = q0 + w * 16 + ln;
      const int k0i = kt * 64;
#pragma unroll
      for (int mt = 0; mt < 4; ++mt)
#pragma unroll
        for (int r = 0; r < 4; ++r) {
          const int key = k0i + mt * 16 + quad * 4 + r;
          const float s = (key > qg) ? -1e30f : (S[mt][r] * 0.125f - 8.f);
          p[mt * 4 + r] = __expf(s);
        }
    } else {
#pragma unroll
      for (int mt = 0; mt < 4; ++mt)
#pragma unroll
        for (int r = 0; r < 4; ++r)
          p[mt * 4 + r] = __expf(S[mt][r] * 0.125f - 8.f);
    }
    float rs = 0.f;
#pragma unroll
    for (int i2 = 0; i2 < 16; ++i2) rs += p[i2];
    l_q += rs;

#pragma unroll
    for (int mt = 0; mt < 4; ++mt) {
      uint2 pk;
      pk.x = (uint32_t)f2bf(p[mt * 4 + 0]) | ((uint32_t)f2bf(p[mt * 4 + 1]) << 16);
      pk.y = (uint32_t)f2bf(p[mt * 4 + 2]) | ((uint32_t)f2bf(p[mt * 4 + 3]) << 16);
      *(uint2*)&Pq[w][ln * 72 + mt * 16 + quad * 4] = pk;
    }

    {
      const uint16_t* pr = &Pq[w][ln * 72 + quad * 8];
      const bf16x8 pf0 = *(const bf16x8*)pr;
      const bf16x8 pf1 = *(const bf16x8*)(pr + 32);
#pragma unroll
      for (int nt = 0; nt < 4; ++nt) {
        const uint16_t* vp = &Vs[(nt * 16 + ln) * 72 + quad * 8];
        O[nt] = __builtin_amdgcn_mfma_f32_16x16x32_bf16(pf0, *(const bf16x8*)vp, O[nt], 0, 0, 0);
        O[nt] = __builtin_amdgcn_mfma_f32_16x16x32_bf16(pf1, *(const bf16x8*)(vp + 32), O[nt], 0, 0, 0);
      }
    }
  }

  l_q += __shfl_xor(l_q, 16);
  l_q += __shfl_xor(l_q, 32);

  if (slot < 0) {
    const int b = bh / HH, h = bh - b * HH;
    f32x4 iv;
#pragma unroll
    for (int r = 0; r < 4; ++r) iv[r] = 1.f / __shfl(l_q, quad * 4 + r);
#pragma unroll
    for (int nt = 0; nt < 4; ++nt) {
      const f32x4 o = O[nt] * iv;
#pragma unroll
      for (int r = 0; r < 4; ++r) {
        const int row = q0 + w * 16 + quad * 4 + r;
        Y[((size_t)(b * LL + row)) * DD + h * DKK + nt * 16 + ln] = f2bf(o[r]);
      }
    }
  } else {
    uint16_t* po = partO + (size_t)slot * 4096;
#pragma unroll
    for (int nt = 0; nt < 4; ++nt)
#pragma unroll
      for (int r = 0; r < 4; ++r)
        po[(w * 16 + quad * 4 + r) * 64 + nt * 16 + ln] = f2bf(O[nt][r]);
    if (quad == 0) partL[slot * 64 + w * 16 + ln] = l_q;
  }
}

// ============================================================================
// Combine bf16 partials: grid (24, B*H), cx -> qt = 8+cx; m = 2/3/4 chunks at
// contiguous bx slots (see attn_mfma mapping). Y = sum(O_i) / sum(l_i).
// ============================================================================
__global__ __launch_bounds__(256) void attn_combine(
    const uint16_t* __restrict__ partO, const float* __restrict__ partL,
    uint16_t* __restrict__ Y)
{
  const int cx = blockIdx.x, bh = blockIdx.y;
  const int qt = 8 + cx, q0 = qt * 64;
  int m, bbx;
  if (cx >= 16)     { m = 4; bbx = (cx - 16) * 4; }
  else if (cx >= 8) { m = 3; bbx = 32 + (cx - 8) * 3; }
  else              { m = 2; bbx = 56 + cx * 2; }
  const int sbase = bh * 72 + bbx;
  const int t = threadIdx.x;
  const int q = t >> 2, d0 = (t & 3) * 16;

  float lsum = 0.f;
  for (int i = 0; i < m; ++i) lsum += partL[(sbase + i) * 64 + q];
  const float inv = 1.f / lsum;

  float acc[16];
#pragma unroll
  for (int k = 0; k < 16; ++k) acc[k] = 0.f;
  for (int i = 0; i < m; ++i) {
    const uint16_t* pp = partO + (size_t)(sbase + i) * 4096 + q * 64 + d0;
    const uint4 v0 = *(const uint4*)(pp + 0);
    const uint4 v1 = *(const uint4*)(pp + 8);
    const uint32_t wv[8] = {v0.x, v0.y, v0.z, v0.w, v1.x, v1.y, v1.z, v1.w};
#pragma unroll
    for (int k = 0; k < 8; ++k) {
      acc[2 * k + 0] += blo(wv[k]);
      acc[2 * k + 1] += bhi(wv[k]);
    }
  }
  uint16_t ov[16];
#pragma unroll
  for (int k = 0; k < 16; ++k) ov[k] = f2bf(acc[k] * inv);
  const int b = bh / HH, h = bh - b * HH;
  uint16_t* yp = Y + ((size_t)(b * LL + q0 + q)) * DD + h * DKK + d0;
  *(uint4*)(yp + 0) = *(const uint4*)&ov[0];
  *(uint4*)(yp + 8) = *(const uint4*)&ov[8];
}

// ============================================================================
extern "C" void kernel_launch(void* const* d_in, const int* in_sizes, int n_in,
                              void* d_out, int out_size, void* d_ws, size_t ws_size,
                              hipStream_t stream) {
  // Resolve inputs by element count (all six distinct) — order-proof.
  const float *x = nullptr, *Wqkv = nullptr, *bqkv = nullptr, *Wo = nullptr, *bo = nullptr;
  for (int i = 0; i < n_in; ++i) {
    switch (in_sizes[i]) {
      case 3145728: x    = (const float*)d_in[i]; break;  // (2,2048,768)
      case 4194304: /* causal mask applied analytically */ break;
      case 1769472: Wqkv = (const float*)d_in[i]; break;  // (768,2304)
      case 2304:    bqkv = (const float*)d_in[i]; break;
      case 589824:  Wo   = (const float*)d_in[i]; break;  // (768,768)
      case 768:     bo   = (const float*)d_in[i]; break;
    }
  }
  float* out = (float*)d_out;

  // ws (bf16 unless noted): xb | WqT | WoT | Q | K | Vt | partO(bf16) | partL(f32)
  uint16_t* xb  = (uint16_t*)d_ws;          // 3,145,728 elems
  uint16_t* WqT = xb  + 3145728;            // 1,769,472
  uint16_t* WoT = WqT + 1769472;            //   589,824
  uint16_t* Qp  = WoT + 589824;             // 3,145,728 each
  uint16_t* Kp  = Qp + 3145728;
  uint16_t* Vtp = Kp + 3145728;             // V transposed (B,H,DK,L)
  uint16_t* partO = Vtp + 3145728;          // 1728 slots x 4096 bf16 (14.2 MB)
  float* partL  = (float*)(partO + (size_t)1728 * 4096);  // 1728 x 64 f32
  uint16_t* Yp  = xb;                       // alias (xb dead after gemm_qkv)

  hipLaunchKernelGGL(cvt_all, dim3(3840), dim3(256), 0, stream, x, Wqkv, Wo, xb, WqT, WoT);
  hipLaunchKernelGGL((gemm_mfma<0, 2304, 768>), dim3(32, 18), dim3(256), 0, stream,
                     xb, WqT, bqkv, (float*)nullptr, Qp, Kp, Vtp);
  hipLaunchKernelGGL(attn_mfma, dim3(80, BB * HH), dim3(256), 0, stream,
                     Qp, Kp, Vtp, Yp, partO, partL);
  hipLaunchKernelGGL(attn_combine, dim3(24, BB * HH), dim3(256), 0, stream,
                     partO, partL, Yp);
  hipLaunchKernelGGL((gemm_mfma<1, 768, 768>), dim3(32, 6), dim3(256), 0, stream,
                     Yp, WoT, bo, out, (uint16_t*)nullptr, (uint16_t*)nullptr, (uint16_t*)nullptr);
}